// Round 8
// baseline (1225.042 us; speedup 1.0000x reference)
//
#include <hip/hip_runtime.h>
#include <math.h>

#define L 8
#define N 32768
#define H 404
#define D 128
#define F 532
#define FP2 576           // F padded to 9*64; wh rows 532..575 zero
#define KT 9              // K-tiles of 64
#define NBLK 1024         // mega grid: 4 blocks/CU x 256 CU, all co-resident
#define GRU_BLK 101       // blocks participating in GRU phase

typedef __attribute__((ext_vector_type(8))) _Float16 half8;
typedef __attribute__((ext_vector_type(4))) float f32x4;

// workspace layout (float offsets)
#define WS_WH      0                        // 128*576 fp16 = 36864 floats
#define WS_HMAXK   (WS_WH + 128*FP2/2)      // 8*128 uint keys
#define WS_HSEL    (WS_HMAXK + L * D)       // 7*128
#define WS_GI      (WS_HSEL + (L - 1) * D)  // 8*1212
#define WS_HBUF    (WS_GI + L * 3 * H)      // 2*404
#define WS_V       (WS_HBUF + 2 * H)        // 532
#define WS_HS      (WS_V + F)               // 128
#define WS_SCAL    (WS_HS + D)              // c, M, S, spare
#define WS_CNT     (WS_SCAL + 4)            // global barrier counter
#define WS_CNT2    (WS_CNT + 1)             // gru sub-barrier counter
#define WS_PM      (WS_CNT2 + 3)            // 1024 partial max
#define WS_PS      (WS_PM + NBLK)           // 1024 partial sum
#define WS_LOGITS  (WS_PS + NBLK)           // 32769

__device__ __forceinline__ unsigned encf(float f) {
    unsigned u = __float_as_uint(f);
    return (u & 0x80000000u) ? ~u : (u | 0x80000000u);
}
__device__ __forceinline__ float decf(unsigned u) {
    unsigned b = (u & 0x80000000u) ? (u ^ 0x80000000u) : ~u;
    return __uint_as_float(b);
}
__device__ __forceinline__ float sigmoidf_(float x) {
    return 1.0f / (1.0f + __expf(-x));
}
__device__ __forceinline__ unsigned pk_f16(float a, float b) {
    auto h = __builtin_amdgcn_cvt_pkrtz(a, b);
    return *(unsigned*)&h;
}
// device-wide barrier: each block adds once; pass when cnt reaches target
__device__ __forceinline__ void gbar(unsigned* cnt, unsigned target) {
    __syncthreads();
    if (threadIdx.x == 0) {
        __hip_atomic_fetch_add(cnt, 1u, __ATOMIC_RELEASE, __HIP_MEMORY_SCOPE_AGENT);
        while (__hip_atomic_load(cnt, __ATOMIC_ACQUIRE, __HIP_MEMORY_SCOPE_AGENT) < target)
            __builtin_amdgcn_s_sleep(2);
    }
    __syncthreads();
}
// online-softmax pair merge across 64 lanes
__device__ __forceinline__ void sm_merge64(float& m, float& s) {
    for (int off = 1; off < 64; off <<= 1) {
        float m2 = __shfl_xor(m, off, 64);
        float s2 = __shfl_xor(s, off, 64);
        float M = fmaxf(m, m2);
        s = s * __expf(m - M) + s2 * __expf(m2 - M);
        m = M;
    }
}

// ---- reset (fresh every launch; ws persists across graph replays) ----
__global__ void k_reset(const float* __restrict__ Wfa, unsigned short* __restrict__ wh,
                        unsigned* __restrict__ keys, unsigned* __restrict__ cnt,
                        unsigned* __restrict__ cnt2) {
    int i = blockIdx.x * 256 + threadIdx.x;
    if (i < L * D) keys[i] = 0u;       // decodes below all finite values
    if (i == 2000) *cnt = 0u;
    if (i == 2001) *cnt2 = 0u;
    if (i < 128 * FP2) {
        int d = i / FP2, f = i % FP2;
        float v = (f < F) ? Wfa[d * F + f] : 0.0f;
        _Float16 h = (_Float16)v;
        wh[i] = *(unsigned short*)&h;
    }
}

// ---- the whole PolicyNet in one kernel ----
__global__ __launch_bounds__(256, 4)
void k_mega(const float* __restrict__ nb, const unsigned short* __restrict__ wh,
            const float* __restrict__ query, const float* __restrict__ pn,
            const int* __restrict__ aid,
            const float* __restrict__ Wih, const float* __restrict__ bih,
            const float* __restrict__ Whh, const float* __restrict__ bhh,
            const float* __restrict__ Wfa, const float* __restrict__ bfa,
            const float* __restrict__ Wfs, const float* __restrict__ bfs,
            const float* __restrict__ Wfp, const float* __restrict__ bfp,
            float* __restrict__ ws, float* __restrict__ out) {
    __shared__ __align__(16) char smem[32768];

    unsigned* hmaxk = (unsigned*)(ws + WS_HMAXK);
    unsigned* cnt   = (unsigned*)(ws + WS_CNT);
    unsigned* cnt2  = (unsigned*)(ws + WS_CNT2);
    float* hsel   = ws + WS_HSEL;
    float* gi     = ws + WS_GI;
    float* hbuf   = ws + WS_HBUF;
    float* v_ws   = ws + WS_V;
    float* hs_ws  = ws + WS_HS;
    float* scal   = ws + WS_SCAL;
    float* pm     = ws + WS_PM;
    float* ps     = ws + WS_PS;
    float* logits = ws + WS_LOGITS;

    const int bid = blockIdx.x;
    const int tid = threadIdx.x;
    const int lane = tid & 63, w4 = tid >> 6;

    // ================= P1: big einsum (2 tiles of 128 rows) =================
    {
        _Float16* As = (_Float16*)smem;             // 16 KB
        _Float16* Bs = (_Float16*)(smem + 16384);   // 16 KB
        const int wm = w4 >> 1, wn = w4 & 1;
        const int lr = lane & 15, kg = lane >> 4;
        const int swz = (lr & 7) << 4;
        int abase[4], bbase[4];
#pragma unroll
        for (int m = 0; m < 4; ++m)
            abase[m] = (wm * 64 + m * 16 + lr) * 128 + ((kg * 16) ^ swz);
#pragma unroll
        for (int n = 0; n < 4; ++n)
            bbase[n] = (wn * 64 + n * 16 + lr) * 128 + ((kg * 16) ^ swz);
        const int ar = tid >> 4, ac4 = tid & 15;
        const int bd = tid >> 3, bc16 = tid & 7;

        for (int tt = 0; tt < 2; ++tt) {
            const int tile = bid + tt * NBLK;       // 0..2047
            const int l_hop = tile >> 8;
            const int row0 = (tile & 255) * 128;
            const float* xbase = nb + ((long)l_hop * N + row0) * F;

            f32x4 acc[4][4];
            float bv[4];
#pragma unroll
            for (int n = 0; n < 4; ++n) bv[n] = bfa[wn * 64 + n * 16 + lr];
#pragma unroll
            for (int m = 0; m < 4; ++m)
#pragma unroll
                for (int n = 0; n < 4; ++n) {
                    acc[m][n][0] = bv[n]; acc[m][n][1] = bv[n];
                    acc[m][n][2] = bv[n]; acc[m][n][3] = bv[n];
                }

            for (int kt = 0; kt < KT; ++kt) {
                const int fc = kt * 64;
                __syncthreads();
#pragma unroll
                for (int it = 0; it < 8; ++it) {
                    int r = ar + it * 16;
                    int fg = fc + ac4 * 4;
                    float4 x = make_float4(0.f, 0.f, 0.f, 0.f);
                    if (fg < F) x = *(const float4*)(xbase + (long)r * F + fg);
                    uint2 u = { pk_f16(x.x, x.y), pk_f16(x.z, x.w) };
                    int wb = r * 128 + ((ac4 * 8) ^ ((r & 7) << 4));
                    *(uint2*)((char*)As + wb) = u;
                }
#pragma unroll
                for (int it = 0; it < 4; ++it) {
                    int dd = bd + it * 32;
                    long so = (long)dd * FP2 + fc + bc16 * 8;
                    int wb = dd * 128 + ((bc16 * 16) ^ ((dd & 7) << 4));
                    *(half8*)((char*)Bs + wb) = *(const half8*)(wh + so);
                }
                __syncthreads();
#pragma unroll
                for (int ks = 0; ks < 2; ++ks) {
                    const int kx = ks << 6;
                    half8 a[4], b[4];
#pragma unroll
                    for (int m = 0; m < 4; ++m)
                        a[m] = *(const half8*)((char*)As + (abase[m] ^ kx));
#pragma unroll
                    for (int n = 0; n < 4; ++n)
                        b[n] = *(const half8*)((char*)Bs + (bbase[n] ^ kx));
#pragma unroll
                    for (int m = 0; m < 4; ++m)
#pragma unroll
                        for (int n = 0; n < 4; ++n)
                            acc[m][n] = __builtin_amdgcn_mfma_f32_16x16x32_f16(a[m], b[n], acc[m][n], 0, 0, 0);
                }
            }
            __syncthreads();

            if (l_hop < L - 1) {
                int br = aid[l_hop] - row0;
                if (br >= 0 && br < 128 && (br >> 6) == wm && ((br >> 2) & 3) == kg) {
                    int msel = (br >> 4) & 3, rsel = br & 3;
#pragma unroll
                    for (int n = 0; n < 4; ++n) {
                        float vsel = 0.f;
#pragma unroll
                        for (int m = 0; m < 4; ++m)
#pragma unroll
                            for (int r = 0; r < 4; ++r)
                                if (m == msel && r == rsel) vsel = acc[m][n][r];
                        hsel[l_hop * D + wn * 64 + n * 16 + lr] = vsel;
                    }
                }
            }

            float cmax[4];
#pragma unroll
            for (int n = 0; n < 4; ++n) {
                float m0 = acc[0][n][0];
#pragma unroll
                for (int m = 0; m < 4; ++m)
#pragma unroll
                    for (int r = 0; r < 4; ++r) m0 = fmaxf(m0, acc[m][n][r]);
                m0 = fmaxf(m0, __shfl_xor(m0, 16, 64));
                m0 = fmaxf(m0, __shfl_xor(m0, 32, 64));
                cmax[n] = m0;
            }
            float* wmaxp = (float*)As;   // reuse As: [2][128]
            if (kg == 0) {
#pragma unroll
                for (int n = 0; n < 4; ++n)
                    wmaxp[wm * 128 + wn * 64 + n * 16 + lr] = cmax[n];
            }
            __syncthreads();
            if (tid < 128) {
                float mval = fmaxf(wmaxp[tid], wmaxp[128 + tid]);
                atomicMax(&hmaxk[l_hop * D + tid], encf(mval));
            }
            __syncthreads();
        }
    }
    gbar(cnt, 1 * NBLK);

    // ================= P2: gi for all 8 GRU steps =================
    if (bid < 303) {
        float (*xs)[3 * D] = (float (*)[3 * D])smem;    // 12 KB
        for (int i = tid; i < L * 3 * D; i += 256) {
            int t = i / (3 * D), k = i % (3 * D);
            float x;
            if (t == 0) {
                x = (k < 2 * D) ? 0.0f : pn[k - 2 * D];
            } else {
                if (k < D)            x = decf(hmaxk[(t - 1) * D + k]);
                else if (k < 2 * D)   x = hsel[(t - 1) * D + (k - D)];
                else                  x = pn[t * D + (k - 2 * D)];
            }
            xs[t][k] = x;
        }
        __syncthreads();
        const int row = bid * 4 + w4;                   // 0..1211
        const float* wr = Wih + (long)row * 3 * D;
        float s[L];
#pragma unroll
        for (int t = 0; t < L; ++t) s[t] = 0.f;
#pragma unroll
        for (int c = 0; c < 6; ++c) {
            int k = lane + c * 64;
            float wv = wr[k];
#pragma unroll
            for (int t = 0; t < L; ++t) s[t] = fmaf(wv, xs[t][k], s[t]);
        }
#pragma unroll
        for (int t = 0; t < L; ++t)
            for (int off = 1; off < 64; off <<= 1) s[t] += __shfl_xor(s[t], off, 64);
        if (lane == 0) {
            float b = bih[row];
#pragma unroll
            for (int t = 0; t < L; ++t) gi[t * 3 * H + row] = s[t] + b;
        }
    }
    gbar(cnt, 2 * NBLK);

    // ================= P3: 8 GRU steps (blocks 0..100) =================
    if (bid < GRU_BLK) {
        const int j = bid * 4 + w4;                     // 0..403
        float wr[7], wz[7], wnn[7];
#pragma unroll
        for (int c = 0; c < 7; ++c) {
            int i = lane + c * 64;
            bool ok = i < H;
            wr[c]  = ok ? Whh[(long)j * H + i]           : 0.f;
            wz[c]  = ok ? Whh[(long)(H + j) * H + i]     : 0.f;
            wnn[c] = ok ? Whh[(long)(2 * H + j) * H + i] : 0.f;
        }
        float b_r = 0.f, b_z = 0.f, b_n = 0.f;
        if (lane == 0) { b_r = bhh[j]; b_z = bhh[H + j]; b_n = bhh[2 * H + j]; }

        for (int t = 0; t < L; ++t) {
            const float* hin = (t == 0) ? query : (hbuf + ((t - 1) & 1) * H);
            float* hout = hbuf + (t & 1) * H;
            float pr = 0.f, pz = 0.f, pn2 = 0.f;
#pragma unroll
            for (int c = 0; c < 7; ++c) {
                int i = lane + c * 64;
                float hv = 0.f;
                if (i < H)
                    hv = (t == 0) ? hin[i]
                                  : __hip_atomic_load(hin + i, __ATOMIC_RELAXED,
                                                      __HIP_MEMORY_SCOPE_AGENT);
                pr  = fmaf(wr[c],  hv, pr);
                pz  = fmaf(wz[c],  hv, pz);
                pn2 = fmaf(wnn[c], hv, pn2);
            }
            for (int off = 1; off < 64; off <<= 1) {
                pr  += __shfl_xor(pr, off, 64);
                pz  += __shfl_xor(pz, off, 64);
                pn2 += __shfl_xor(pn2, off, 64);
            }
            if (lane == 0) {
                const float* gt = gi + t * 3 * H;
                float hprev = (t == 0) ? hin[j]
                                       : __hip_atomic_load(hin + j, __ATOMIC_RELAXED,
                                                           __HIP_MEMORY_SCOPE_AGENT);
                float r  = sigmoidf_(gt[j] + pr + b_r);
                float z  = sigmoidf_(gt[H + j] + pz + b_z);
                float nn = tanhf(gt[2 * H + j] + r * (pn2 + b_n));
                float hv = (1.0f - z) * nn + z * hprev;
                __hip_atomic_store(hout + j, hv, __ATOMIC_RELAXED,
                                   __HIP_MEMORY_SCOPE_AGENT);
            }
            if (t < L - 1) {
                __syncthreads();
                if (tid == 0) {
                    __hip_atomic_fetch_add(cnt2, 1u, __ATOMIC_RELEASE,
                                           __HIP_MEMORY_SCOPE_AGENT);
                    unsigned target = (unsigned)GRU_BLK * (t + 1);
                    while (__hip_atomic_load(cnt2, __ATOMIC_ACQUIRE,
                                             __HIP_MEMORY_SCOPE_AGENT) < target)
                        __builtin_amdgcn_s_sleep(2);
                }
                __syncthreads();
            }
        }
    }
    gbar(cnt, 3 * NBLK);

    // ================= P4: hSt = W_fs qt + b_fs (blocks 0..31) =================
    if (bid < 32) {
        const float* qt = hbuf + 1 * H;                 // (L-1)&1 == 1
        int d = bid * 4 + w4;                           // 0..127
        float s = 0.f;
#pragma unroll
        for (int c = 0; c < 7; ++c) {
            int i = lane + c * 64;
            if (i < H) s = fmaf(qt[i], Wfs[(long)d * H + i], s);
        }
        for (int off = 1; off < 64; off <<= 1) s += __shfl_xor(s, off, 64);
        if (lane == 0) hs_ws[d] = s + bfs[d];
    }
    gbar(cnt, 4 * NBLK);

    // ================= P5: v = W_fa^T hSt ; u0 ; c =================
    if (bid < 5) {
        if (tid < 128) {
            int f = bid * 128 + tid;
            if (f < F) {
                float s = 0.f;
#pragma unroll 16
                for (int d = 0; d < D; ++d) s = fmaf(hs_ws[d], Wfa[(long)d * F + f], s);
                v_ws[f] = s;
            }
        }
    } else if (bid == 5 && tid == 0) {
        float s = bfp[0], c2 = 0.f;
        for (int d = 0; d < D; ++d) {
            s  = fmaf(hs_ws[d], Wfp[d], s);
            s  = fmaf(decf(hmaxk[(L - 1) * D + d]), Wfp[D + d], s);
            c2 = fmaf(hs_ws[d], bfa[d], c2);
        }
        logits[0] = s;
        scal[0] = c2;
    }
    gbar(cnt, 5 * NBLK);

    // ================= P6: uks logits + per-block softmax partials =================
    {
        float* vlds = (float*)smem;                     // 532 floats
        float* wpm  = (float*)(smem + 2304);            // 4
        float* wps  = (float*)(smem + 2368);            // 4
        for (int i = tid; i < F; i += 256) vlds[i] = v_ws[i];
        __syncthreads();
        const float cadd = scal[0];
        const float* nb7 = nb + (long)(L - 1) * N * F;
        float mw = -3.4e38f, sw = 0.f;
        for (int r = 0; r < 8; ++r) {
            int n = bid * 32 + w4 * 8 + r;              // 0..32767
            const float* rowp = nb7 + (long)n * F;
            float s = 0.f;
#pragma unroll
            for (int c = 0; c < 9; ++c) {
                int f = lane + c * 64;
                if (f < F) s = fmaf(vlds[f], rowp[f], s);
            }
            for (int off = 1; off < 64; off <<= 1) s += __shfl_xor(s, off, 64);
            if (lane == 0) {
                float tot = s + cadd;
                logits[1 + n] = tot;
                if (tot > mw) { sw = sw * __expf(mw - tot) + 1.0f; mw = tot; }
                else          { sw += __expf(tot - mw); }
            }
        }
        if (lane == 0) { wpm[w4] = mw; wps[w4] = sw; }
        __syncthreads();
        if (tid == 0) {
            float M = -3.4e38f, S = 0.f;
#pragma unroll
            for (int k = 0; k < 4; ++k) {
                float m2 = wpm[k], s2 = wps[k];
                float Mn = fmaxf(M, m2);
                S = S * __expf(M - Mn) + s2 * __expf(m2 - Mn);
                M = Mn;
            }
            if (bid == 0) {   // fold u0 in
                float t0 = logits[0];
                float Mn = fmaxf(M, t0);
                S = S * __expf(M - Mn) + __expf(t0 - Mn);
                M = Mn;
            }
            pm[bid] = M; ps[bid] = S;
        }
    }
    gbar(cnt, 6 * NBLK);

    // ================= P7: reduce 1024 partials (block 0) =================
    if (bid == 0) {
        float* rm = (float*)smem;
        float* rs = rm + 8;
        float M = -3.4e38f, S = 0.f;
#pragma unroll
        for (int k = 0; k < 4; ++k) {
            int i = tid * 4 + k;
            float m2 = pm[i], s2 = ps[i];
            float Mn = fmaxf(M, m2);
            S = S * __expf(M - Mn) + s2 * __expf(m2 - Mn);
            M = Mn;
        }
        sm_merge64(M, S);
        if (lane == 0) { rm[w4] = M; rs[w4] = S; }
        __syncthreads();
        if (tid == 0) {
            float Mf = -3.4e38f, Sf = 0.f;
#pragma unroll
            for (int k = 0; k < 4; ++k) {
                float Mn = fmaxf(Mf, rm[k]);
                Sf = Sf * __expf(Mf - Mn) + rs[k] * __expf(rm[k] - Mn);
                Mf = Mn;
            }
            scal[1] = Mf; scal[2] = Sf;
        }
    }
    gbar(cnt, 7 * NBLK);

    // ================= P8: write softmax =================
    {
        int i = bid * 256 + tid;
        if (i <= N) out[i] = __expf(logits[i] - scal[1]) / scal[2];
    }
}

extern "C" void kernel_launch(void* const* d_in, const int* in_sizes, int n_in,
                              void* d_out, int out_size, void* d_ws, size_t ws_size,
                              hipStream_t stream) {
    const float* query = (const float*)d_in[0];
    const float* pn    = (const float*)d_in[1];
    const float* nb    = (const float*)d_in[2];
    const int*   aid   = (const int*)d_in[3];
    const float* Wih   = (const float*)d_in[4];
    const float* Whh   = (const float*)d_in[5];
    const float* bih   = (const float*)d_in[6];
    const float* bhh   = (const float*)d_in[7];
    const float* Wfa   = (const float*)d_in[8];
    const float* bfa   = (const float*)d_in[9];
    const float* Wfs   = (const float*)d_in[10];
    const float* bfs   = (const float*)d_in[11];
    const float* Wfp   = (const float*)d_in[12];
    const float* bfp   = (const float*)d_in[13];

    float* ws = (float*)d_ws;
    unsigned short* wh    = (unsigned short*)(ws + WS_WH);
    unsigned*       hmaxk = (unsigned*)(ws + WS_HMAXK);
    unsigned*       cnt   = (unsigned*)(ws + WS_CNT);
    unsigned*       cnt2  = (unsigned*)(ws + WS_CNT2);
    float*          out   = (float*)d_out;

    k_reset<<<288, 256, 0, stream>>>(Wfa, wh, hmaxk, cnt, cnt2);
    k_mega <<<NBLK, 256, 0, stream>>>(nb, wh, query, pn, aid,
                                      Wih, bih, Whh, bhh, Wfa, bfa,
                                      Wfs, bfs, Wfp, bfp, ws, out);
}

// Round 9
// 226.044 us; speedup vs baseline: 5.4195x; 5.4195x over previous
//
#include <hip/hip_runtime.h>
#include <math.h>

#define L 8
#define N 32768
#define H 404
#define D 128
#define F 532
#define KT 9              // K-tiles of 64 (64*9=576; cols >=532 are zero in B)
#define GRU_BLOCKS 101    // one wave per hidden index

typedef __attribute__((ext_vector_type(8))) _Float16 half8;
typedef __attribute__((ext_vector_type(4))) float f32x4;
typedef __attribute__((address_space(3))) unsigned int as3_u32;
typedef __attribute__((address_space(1))) unsigned int as1_u32;

// workspace layout (float offsets)
#define WS_WH2     0                        // 9*128*64 fp16 = 36864 floats (pre-swizzled B tiles)
#define WS_HMAXK   (WS_WH2 + 36864)         // 8*128 uint keys
#define WS_HSEL    (WS_HMAXK + L * D)       // 7*128
#define WS_GI      (WS_HSEL + (L - 1) * D)  // 8*1212
#define WS_HBUF    (WS_GI + L * 3 * H)      // 2*404
#define WS_V       (WS_HBUF + 2 * H)        // 532
#define WS_HS      (WS_V + F)               // 128
#define WS_SCAL    (WS_HS + D)              // c, M, S, spare
#define WS_CNT     (WS_SCAL + 4)            // gru barrier counter
#define WS_LOGITS  (WS_CNT + 4)             // 32769

__device__ __forceinline__ unsigned encf(float f) {
    unsigned u = __float_as_uint(f);
    return (u & 0x80000000u) ? ~u : (u | 0x80000000u);
}
__device__ __forceinline__ float decf(unsigned u) {
    unsigned b = (u & 0x80000000u) ? (u ^ 0x80000000u) : ~u;
    return __uint_as_float(b);
}
__device__ __forceinline__ float sigmoidf_(float x) {
    return 1.0f / (1.0f + __expf(-x));
}
__device__ __forceinline__ unsigned pk_f16(float a, float b) {
    auto h = __builtin_amdgcn_cvt_pkrtz(a, b);
    return *(unsigned*)&h;
}
__device__ __forceinline__ half8 pack8(float4 x0, float4 x1) {
    uint4 u = { pk_f16(x0.x, x0.y), pk_f16(x0.z, x0.w),
                pk_f16(x1.x, x1.y), pk_f16(x1.z, x1.w) };
    return *(half8*)&u;
}
// async global->LDS, 16 B per lane; LDS dest = wave-uniform base + lane*16
__device__ __forceinline__ void gld16(const void* g, void* l) {
    __builtin_amdgcn_global_load_lds((const as1_u32*)g, (as3_u32*)l, 16, 0, 0);
}

// ---- prep: build pre-swizzled fp16 B tiles wh2[kt][col][chunk]; init keys ----
// chunk j of (kt,col) holds original k-chunk (j ^ (col&7)): so staged LDS (linear)
// ends up XOR-swizzled, matching the swizzled consume reads.
__global__ void k_prep(const float* __restrict__ Wfa, unsigned short* __restrict__ wh2,
                       unsigned* __restrict__ keys, unsigned* __restrict__ cnt) {
    int i = blockIdx.x * 256 + threadIdx.x;
    if (i < L * D) keys[i] = 0u;           // decodes below all finite values
    if (i == 2000) *cnt = 0u;
    if (i >= KT * 128 * 8) return;
    int kt = i / (128 * 8);
    int rem = i - kt * 128 * 8;
    int c = rem >> 3, j = rem & 7;
    int k0 = kt * 64 + (j ^ (c & 7)) * 8;
    unsigned short v[8];
#pragma unroll
    for (int e = 0; e < 8; ++e) {
        int k = k0 + e;
        float x = (k < F) ? Wfa[c * F + k] : 0.0f;
        _Float16 h = (_Float16)x;
        v[e] = *(unsigned short*)&h;
    }
    *(uint4*)(wh2 + (long)i * 8) = *(uint4*)v;
}

// ---- big einsum: async global_load_lds staging, consume-side fp32->fp16 cvt ----
// grid 2048: l = bid>>8, 128-row chunk = bid&255. 4 waves, each 64x64 output.
// LDS: A fp32 [128][64] (32 KB, XOR-swizzled via pre-swizzled SOURCE addresses),
//      B fp16 [128][64] (16 KB, linear copy of pre-swizzled wh2 tile).
__global__ __launch_bounds__(256, 3)
void k_big(const float* __restrict__ nb, const unsigned short* __restrict__ wh2,
           const float* __restrict__ bfa, const int* __restrict__ aid,
           unsigned* __restrict__ hmaxk, float* __restrict__ hsel) {
    __shared__ float As[128 * 64];          // 32 KB, row = 256 B = 16 chunks
    __shared__ unsigned short Bs[128 * 64]; // 16 KB, row = 128 B = 8 chunks

    const int bid = blockIdx.x;
    const int l_hop = bid >> 8;
    const int row0 = (bid & 255) * 128;
    const int tid = threadIdx.x;
    const int lane = tid & 63, w = tid >> 6;
    const int wm = w >> 1, wn = w & 1;
    const int lr = lane & 15, kg = lane >> 4;

    const float* xbase = nb + ((long)l_hop * N + row0) * F;

    // acc init = bias (broadcast down each output column d)
    f32x4 acc[4][4];
    float bv[4];
#pragma unroll
    for (int n = 0; n < 4; ++n) bv[n] = bfa[wn * 64 + n * 16 + lr];
#pragma unroll
    for (int m = 0; m < 4; ++m)
#pragma unroll
        for (int n = 0; n < 4; ++n) {
            acc[m][n][0] = bv[n]; acc[m][n][1] = bv[n];
            acc[m][n][2] = bv[n]; acc[m][n][3] = bv[n];
        }

    const int srow = lane >> 4;        // A-stage: sub-row within wave's 4 rows
    const int scp  = lane & 15;        // A-stage: dest chunk'

    for (int kt = 0; kt < KT; ++kt) {
        const int fc = kt * 64;
        __syncthreads();               // prior MFMA reads done -> LDS writable

        // ---- stage A: 8 async issues/thread; dest linear, source pre-swizzled ----
#pragma unroll
        for (int it = 0; it < 8; ++it) {
            int rbase = it * 16 + w * 4;
            int row = rbase + srow;
            int cg = scp ^ (row & 7);              // global chunk for this dest slot
            int col0 = fc + cg * 4;
            const float* src = xbase + (long)row * F + ((col0 < F) ? col0 : 0);
            gld16(src, (char*)As + rbase * 256);
        }
        // ---- stage B: 4 async issues/thread; fully linear (wh2 pre-swizzled) ----
#pragma unroll
        for (int it = 0; it < 4; ++it) {
            int rb = it * 32 + w * 8;
            const char* src = (const char*)wh2 + (long)kt * 16384 + rb * 128 + lane * 16;
            gld16(src, (char*)Bs + rb * 128);
        }
        __syncthreads();               // vmcnt(0) drained by compiler before barrier

        // ---- 2 K-steps of 32: swizzled reads, cvt on consume, MFMA ----
#pragma unroll
        for (int ks = 0; ks < 2; ++ks) {
            half8 b[4];
#pragma unroll
            for (int n = 0; n < 4; ++n) {
                int col = wn * 64 + n * 16 + lr;
                int ch = (ks * 4 + kg) ^ (col & 7);
                b[n] = *(const half8*)((const char*)Bs + col * 128 + ch * 16);
            }
#pragma unroll
            for (int m = 0; m < 4; ++m) {
                int row = wm * 64 + m * 16 + lr;
                int c0 = ks * 8 + kg * 2;
                const char* base = (const char*)As + row * 256;
                float4 x0 = *(const float4*)(base + (((c0)     ^ (row & 7)) << 4));
                float4 x1 = *(const float4*)(base + (((c0 + 1) ^ (row & 7)) << 4));
                half8 a = pack8(x0, x1);
#pragma unroll
                for (int n = 0; n < 4; ++n)
                    acc[m][n] = __builtin_amdgcn_mfma_f32_16x16x32_f16(a, b[n], acc[m][n], 0, 0, 0);
            }
        }
    }

    __syncthreads();   // LDS reads done; reuse As for cross-wave max

    // selected-action row (compile-time acc indexing)
    if (l_hop < L - 1) {
        int br = aid[l_hop] - row0;
        if (br >= 0 && br < 128 && (br >> 6) == wm && ((br >> 2) & 3) == kg) {
            int msel = (br >> 4) & 3, rsel = br & 3;
#pragma unroll
            for (int n = 0; n < 4; ++n) {
                float vsel = 0.f;
#pragma unroll
                for (int m = 0; m < 4; ++m)
#pragma unroll
                    for (int r = 0; r < 4; ++r)
                        if (m == msel && r == rsel) vsel = acc[m][n][r];
                hsel[l_hop * D + wn * 64 + n * 16 + lr] = vsel;
            }
        }
    }

    // column max: thread-local -> cross-lane-group shfl -> cross-wave LDS -> atomic
    float cmax[4];
#pragma unroll
    for (int n = 0; n < 4; ++n) {
        float m0 = acc[0][n][0];
#pragma unroll
        for (int m = 0; m < 4; ++m)
#pragma unroll
            for (int r = 0; r < 4; ++r) m0 = fmaxf(m0, acc[m][n][r]);
        m0 = fmaxf(m0, __shfl_xor(m0, 16, 64));
        m0 = fmaxf(m0, __shfl_xor(m0, 32, 64));
        cmax[n] = m0;
    }
    float* wmaxp = (float*)As;   // [2][128]
    if (kg == 0) {
#pragma unroll
        for (int n = 0; n < 4; ++n)
            wmaxp[wm * 128 + wn * 64 + n * 16 + lr] = cmax[n];
    }
    __syncthreads();
    if (tid < 128) {
        float mval = fmaxf(wmaxp[tid], wmaxp[128 + tid]);
        atomicMax(&hmaxk[l_hop * D + tid], encf(mval));
    }
}

// ---- gi for all 8 GRU steps: one wave per output row, coalesced W_ih reads ----
__global__ void k_gi(const float* __restrict__ Wih, const float* __restrict__ bih,
                     const float* __restrict__ pn, const unsigned* __restrict__ hmaxk,
                     const float* __restrict__ hsel, float* __restrict__ gi) {
    __shared__ float xs[L][3 * D];
    const int tid = threadIdx.x;
    for (int i = tid; i < L * 3 * D; i += 256) {
        int t = i / (3 * D), k = i % (3 * D);
        float x;
        if (t == 0) {
            x = (k < 2 * D) ? 0.0f : pn[k - 2 * D];
        } else {
            if (k < D)            x = decf(hmaxk[(t - 1) * D + k]);
            else if (k < 2 * D)   x = hsel[(t - 1) * D + (k - D)];
            else                  x = pn[t * D + (k - 2 * D)];
        }
        xs[t][k] = x;
    }
    __syncthreads();

    const int lane = tid & 63;
    const int row = blockIdx.x * 4 + (tid >> 6);   // 0..1211
    const float* wr = Wih + (long)row * 3 * D;
    float s[L];
#pragma unroll
    for (int t = 0; t < L; ++t) s[t] = 0.f;
#pragma unroll
    for (int c = 0; c < 6; ++c) {
        int k = lane + c * 64;
        float wv = wr[k];
#pragma unroll
        for (int t = 0; t < L; ++t) s[t] = fmaf(wv, xs[t][k], s[t]);
    }
#pragma unroll
    for (int t = 0; t < L; ++t)
        for (int off = 1; off < 64; off <<= 1) s[t] += __shfl_xor(s[t], off, 64);
    if (lane == 0) {
        float b = bih[row];
#pragma unroll
        for (int t = 0; t < L; ++t) gi[t * 3 * H + row] = s[t] + b;
    }
}

// ---- all 8 GRU steps in ONE kernel; one wave per hidden j; grid barrier ----
__global__ __launch_bounds__(256, 1)
void k_gru(const float* __restrict__ Whh, const float* __restrict__ bhh,
           const float* __restrict__ gi, const float* __restrict__ query,
           float* __restrict__ hbuf, unsigned* __restrict__ cnt) {
    const int tid = threadIdx.x;
    const int lane = tid & 63;
    const int j = blockIdx.x * 4 + (tid >> 6);     // 0..403

    float wr[7], wz[7], wnn[7];
#pragma unroll
    for (int c = 0; c < 7; ++c) {
        int i = lane + c * 64;
        bool ok = i < H;
        wr[c]  = ok ? Whh[(long)j * H + i]           : 0.f;
        wz[c]  = ok ? Whh[(long)(H + j) * H + i]     : 0.f;
        wnn[c] = ok ? Whh[(long)(2 * H + j) * H + i] : 0.f;
    }
    float b_r = 0.f, b_z = 0.f, b_n = 0.f;
    if (lane == 0) { b_r = bhh[j]; b_z = bhh[H + j]; b_n = bhh[2 * H + j]; }

    for (int t = 0; t < L; ++t) {
        const float* hin = (t == 0) ? query : (hbuf + ((t - 1) & 1) * H);
        float* hout = hbuf + (t & 1) * H;
        float pr = 0.f, pz = 0.f, pn2 = 0.f;
#pragma unroll
        for (int c = 0; c < 7; ++c) {
            int i = lane + c * 64;
            float hv = 0.f;
            if (i < H)
                hv = (t == 0) ? hin[i]
                              : __hip_atomic_load(hin + i, __ATOMIC_RELAXED,
                                                  __HIP_MEMORY_SCOPE_AGENT);
            pr  = fmaf(wr[c],  hv, pr);
            pz  = fmaf(wz[c],  hv, pz);
            pn2 = fmaf(wnn[c], hv, pn2);
        }
        for (int off = 1; off < 64; off <<= 1) {
            pr  += __shfl_xor(pr, off, 64);
            pz  += __shfl_xor(pz, off, 64);
            pn2 += __shfl_xor(pn2, off, 64);
        }
        if (lane == 0) {
            const float* gt = gi + t * 3 * H;
            float hprev = (t == 0) ? hin[j]
                                   : __hip_atomic_load(hin + j, __ATOMIC_RELAXED,
                                                       __HIP_MEMORY_SCOPE_AGENT);
            float r  = sigmoidf_(gt[j] + pr + b_r);
            float z  = sigmoidf_(gt[H + j] + pz + b_z);
            float nn = tanhf(gt[2 * H + j] + r * (pn2 + b_n));
            float hv = (1.0f - z) * nn + z * hprev;
            __hip_atomic_store(hout + j, hv, __ATOMIC_RELAXED,
                               __HIP_MEMORY_SCOPE_AGENT);
        }
        if (t < L - 1) {
            __syncthreads();
            if (tid == 0) {
                __hip_atomic_fetch_add(cnt, 1u, __ATOMIC_RELEASE,
                                       __HIP_MEMORY_SCOPE_AGENT);
                unsigned target = (unsigned)GRU_BLOCKS * (t + 1);
                while (__hip_atomic_load(cnt, __ATOMIC_ACQUIRE,
                                         __HIP_MEMORY_SCOPE_AGENT) < target)
                    __builtin_amdgcn_s_sleep(2);
            }
            __syncthreads();
        }
    }
}

// ---- hSt + v + u0 + c in one block (1024 thr, 16 waves) ----
__global__ void k_final(const float* __restrict__ qt, const float* __restrict__ Wfs,
                        const float* __restrict__ bfs, const float* __restrict__ Wfp,
                        const float* __restrict__ bfp, const float* __restrict__ bfa,
                        const float* __restrict__ Wfa, const unsigned* __restrict__ hmaxk,
                        float* __restrict__ v, float* __restrict__ scal,
                        float* __restrict__ logits) {
    __shared__ float hs[D];
    int tid = threadIdx.x, lane = tid & 63, wid = tid >> 6;   // 16 waves
#pragma unroll
    for (int dd = 0; dd < 8; ++dd) {
        int d = wid * 8 + dd;
        float s = 0.f;
#pragma unroll
        for (int c = 0; c < 7; ++c) {
            int i = lane + c * 64;
            if (i < H) s = fmaf(qt[i], Wfs[(long)d * H + i], s);
        }
        for (int off = 1; off < 64; off <<= 1) s += __shfl_xor(s, off, 64);
        if (lane == 0) hs[d] = s + bfs[d];
    }
    __syncthreads();
    if (tid < F) {
        float s = 0.f;
#pragma unroll 16
        for (int d = 0; d < D; ++d) s = fmaf(hs[d], Wfa[(long)d * F + tid], s);
        v[tid] = s;
    } else if (tid == F) {
        float s = bfp[0];
        for (int d = 0; d < D; ++d) {
            s = fmaf(hs[d], Wfp[d], s);
            s = fmaf(decf(hmaxk[(L - 1) * D + d]), Wfp[D + d], s);
        }
        logits[0] = s;
    } else if (tid == F + 1) {
        float c2 = 0.f;
        for (int d = 0; d < D; ++d) c2 = fmaf(hs[d], bfa[d], c2);
        scal[0] = c2;
    }
}

// ---- uks logits (exact fp32 path); one wave per neighbor row of hop 7 ----
__global__ void k_uks(const float* __restrict__ nb7, const float* __restrict__ v,
                      const float* __restrict__ scal, float* __restrict__ logits) {
    long n = (long)blockIdx.x * 4 + (threadIdx.x >> 6);
    int lane = threadIdx.x & 63;
    const float* row = nb7 + n * F;
    float s = 0.f;
    for (int f = lane; f < F; f += 64) s = fmaf(v[f], row[f], s);
    for (int off = 1; off < 64; off <<= 1) s += __shfl_xor(s, off, 64);
    if (lane == 0) logits[1 + n] = s + scal[0];
}

// ---- softmax reduce over 32769 (single block, 1024 thr) ----
__global__ void k_sm12(const float* __restrict__ logits, float* __restrict__ scal) {
    __shared__ float sm[16], ss[16];
    int tid = threadIdx.x, lane = tid & 63, wid = tid >> 6;
    float m = -3.4e38f, s = 0.f;
    for (int i = tid; i <= N; i += 1024) {
        float x = logits[i];
        if (x > m) { s = s * __expf(m - x) + 1.0f; m = x; }
        else       { s += __expf(x - m); }
    }
    for (int off = 1; off < 64; off <<= 1) {
        float m2 = __shfl_xor(m, off, 64);
        float s2 = __shfl_xor(s, off, 64);
        float M = fmaxf(m, m2);
        s = s * __expf(m - M) + s2 * __expf(m2 - M);
        m = M;
    }
    if (lane == 0) { sm[wid] = m; ss[wid] = s; }
    __syncthreads();
    if (tid == 0) {
        float M = sm[0], S = 0.f;
        for (int k = 1; k < 16; ++k) M = fmaxf(M, sm[k]);
        for (int k = 0; k < 16; ++k) S += ss[k] * __expf(sm[k] - M);
        scal[1] = M; scal[2] = S;
    }
}

__global__ void k_sm3(const float* __restrict__ logits, const float* __restrict__ scal,
                      float* __restrict__ out) {
    int i = blockIdx.x * 256 + threadIdx.x;
    if (i <= N) out[i] = __expf(logits[i] - scal[1]) / scal[2];
}

extern "C" void kernel_launch(void* const* d_in, const int* in_sizes, int n_in,
                              void* d_out, int out_size, void* d_ws, size_t ws_size,
                              hipStream_t stream) {
    const float* query = (const float*)d_in[0];
    const float* pn    = (const float*)d_in[1];
    const float* nb    = (const float*)d_in[2];
    const int*   aid   = (const int*)d_in[3];
    const float* Wih   = (const float*)d_in[4];
    const float* Whh   = (const float*)d_in[5];
    const float* bih   = (const float*)d_in[6];
    const float* bhh   = (const float*)d_in[7];
    const float* Wfa   = (const float*)d_in[8];
    const float* bfa   = (const float*)d_in[9];
    const float* Wfs   = (const float*)d_in[10];
    const float* bfs   = (const float*)d_in[11];
    const float* Wfp   = (const float*)d_in[12];
    const float* bfp   = (const float*)d_in[13];

    float* ws = (float*)d_ws;
    unsigned short* wh2   = (unsigned short*)(ws + WS_WH2);
    unsigned*       hmaxk = (unsigned*)(ws + WS_HMAXK);
    unsigned*       cnt   = (unsigned*)(ws + WS_CNT);
    float* hsel   = ws + WS_HSEL;
    float* gi     = ws + WS_GI;
    float* hbuf   = ws + WS_HBUF;
    float* v      = ws + WS_V;
    float* scal   = ws + WS_SCAL;
    float* logits = ws + WS_LOGITS;
    float* out    = (float*)d_out;

    k_prep<<<(KT * 128 * 8 + 255) / 256, 256, 0, stream>>>(Wfa, wh2, hmaxk, cnt);
    k_big <<<L * 256, 256, 0, stream>>>(nb, wh2, bfa, aid, hmaxk, hsel);
    k_gi  <<<303, 256, 0, stream>>>(Wih, bih, pn, hmaxk, hsel, gi);
    k_gru <<<GRU_BLOCKS, 256, 0, stream>>>(Whh, bhh, gi, query, hbuf, cnt);

    const float* qt = hbuf + ((L - 1) & 1) * H;   // hbuf[1]
    k_final<<<1, 1024, 0, stream>>>(qt, Wfs, bfs, Wfp, bfp, bfa, Wfa, hmaxk, v, scal, logits);
    k_uks  <<<N / 4, 256, 0, stream>>>(nb + (long)(L - 1) * N * F, v, scal, logits);

    k_sm12<<<1, 1024, 0, stream>>>(logits, scal);
    k_sm3 <<<(N + 1 + 255) / 256, 256, 0, stream>>>(logits, scal, out);
}